// Round 6
// baseline (532.022 us; speedup 1.0000x reference)
//
#include <hip/hip_runtime.h>
#include <cstdint>

#define B_SZ   16384
#define H_SZ   512
#define DIN    256
#define TEMB   16
#define KP     1344          // packed K: x[0,256) h[256,768) c[768,1280) delt[1280,1296) pad[1296,1344)
#define KPB    2688          // KP*2 bytes per row
#define BH     8388608L      // B_SZ*H_SZ
#define SLOT   40960         // LDS slot: A 16 KB (256 rows x 64 B) + W 24 KB (6 g x 64 cols x 64 B)
#define GSTR   1376256       // 512*KPB: gate stride in Wp bytes

typedef __attribute__((ext_vector_type(4))) float f32x4;
typedef __bf16 bf16x8 __attribute__((ext_vector_type(8)));

typedef const __attribute__((address_space(1))) unsigned int gu32_t;
typedef __attribute__((address_space(3)))       unsigned int lu32_t;

__device__ __forceinline__ void gld16(const void* g, void* l) {
  __builtin_amdgcn_global_load_lds((gu32_t*)(uintptr_t)g,
                                   (lu32_t*)(unsigned int)(uintptr_t)l, 16, 0, 0);
}

__device__ __forceinline__ unsigned short f2bf(float f) {
  unsigned int u = __float_as_uint(f);
  u += 0x7FFFu + ((u >> 16) & 1u);   // RNE; inputs finite
  return (unsigned short)(u >> 16);
}

__device__ __forceinline__ float sigm(float v)  { return 1.0f / (1.0f + __expf(-v)); }
__device__ __forceinline__ float tanhx(float v) { return 2.0f / (1.0f + __expf(-2.0f * v)) - 1.0f; }

// ---------------- prep: pack A = [x|h|c|delt|0] as bf16 [B][KP] ----------------
__global__ void prep_a_kernel(const float* __restrict__ x, const float* __restrict__ h,
                              const float* __restrict__ c, const float* __restrict__ dl,
                              unsigned short* __restrict__ Ap) {
  long idx = (long)blockIdx.x * 256 + threadIdx.x;
  const long n4 = (long)B_SZ * KP / 4;
  if (idx >= n4) return;
  int row = (int)(idx / (KP / 4));
  int k4  = (int)(idx % (KP / 4)) * 4;
  float4 v = make_float4(0.f, 0.f, 0.f, 0.f);
  if (k4 < 256)       v = *(const float4*)(x  + (long)row * DIN  + k4);
  else if (k4 < 768)  v = *(const float4*)(h  + (long)row * H_SZ + (k4 - 256));
  else if (k4 < 1280) v = *(const float4*)(c  + (long)row * H_SZ + (k4 - 768));
  else if (k4 < 1296) v = *(const float4*)(dl + (long)row * TEMB + (k4 - 1280));
  ushort4 o;
  o.x = f2bf(v.x); o.y = f2bf(v.y); o.z = f2bf(v.z); o.w = f2bf(v.w);
  *(ushort4*)(Ap + idx * 4) = o;
}

// ---------------- prep: pack Wp[6][512][KP] bf16 ----------------
__global__ void prep_w_kernel(const float* __restrict__ Wix, const float* __restrict__ Wih, const float* __restrict__ Wic,
                              const float* __restrict__ Wfx, const float* __restrict__ Wfh, const float* __restrict__ Wfc,
                              const float* __restrict__ Wtx, const float* __restrict__ Wtt,
                              const float* __restrict__ Wcx, const float* __restrict__ Wch,
                              const float* __restrict__ Wox, const float* __restrict__ Woh,
                              const float* __restrict__ Woc, const float* __restrict__ Wot,
                              unsigned short* __restrict__ Wp) {
  long idx = (long)blockIdx.x * 256 + threadIdx.x;
  const long n4 = 6L * H_SZ * KP / 4;
  if (idx >= n4) return;
  int k4   = (int)(idx % (KP / 4)) * 4;
  int rest = (int)(idx / (KP / 4));
  int n = rest & 511;
  int g = rest >> 9;
  const float* src = nullptr; long o = 0;
  if (g == 0) {
    if (k4 < 256)       { src = Wix; o = (long)n * 256 + k4; }
    else if (k4 < 768)  { src = Wih; o = (long)n * 512 + (k4 - 256); }
    else if (k4 < 1280) { src = Wic; o = (long)n * 512 + (k4 - 768); }
  } else if (g == 1) {
    if (k4 < 256)       { src = Wfx; o = (long)n * 256 + k4; }
    else if (k4 < 768)  { src = Wfh; o = (long)n * 512 + (k4 - 256); }
    else if (k4 < 1280) { src = Wfc; o = (long)n * 512 + (k4 - 768); }
  } else if (g == 2) {
    if (k4 < 256)       { src = Wtx; o = (long)n * 256 + k4; }
  } else if (g == 3) {
    if (k4 < 256)       { src = Wcx; o = (long)n * 256 + k4; }
    else if (k4 < 768)  { src = Wch; o = (long)n * 512 + (k4 - 256); }
  } else if (g == 4) {
    if (k4 < 256)       { src = Wox; o = (long)n * 256 + k4; }
    else if (k4 < 768)  { src = Woh; o = (long)n * 512 + (k4 - 256); }
    else if (k4 < 1280) { src = Woc; o = (long)n * 512 + (k4 - 768); }
    else if (k4 < 1296) { src = Wot; o = (long)n * 16 + (k4 - 1280); }
  } else {
    if (k4 >= 1280 && k4 < 1296) { src = Wtt; o = (long)n * 16 + (k4 - 1280); }
  }
  float4 v = make_float4(0.f, 0.f, 0.f, 0.f);
  if (src) v = *(const float4*)(src + o);
  ushort4 u;
  u.x = f2bf(v.x); u.y = f2bf(v.y); u.z = f2bf(v.z); u.w = f2bf(v.w);
  *(ushort4*)(Wp + idx * 4) = u;
}

// LDS layout per slot (K-phase = 32 elems = 64 B per row):
//   A: byte = row*64 + ((kgrp + (row>>1))&3)*16,  row in [0,256)
//   W: byte = 16384 + g*4096 + col*64 + ((kgrp+(col>>1))&3)*16
// gld16 writes 1KB chunks (16 rows/cols) linearly; per-lane source granule is
// pre-permuted (kslot) so the stored layout matches (linear-dest rule, r4-verified).

// stage phase h into slot byte-base sb. Waves 4-7: A (4 chunks each); waves 0-3: W.
template<unsigned SMASK>
__device__ __forceinline__ void stage(char* lds, int sb, int h,
                                      const char* sA4, const char* sW, int wid) {
  const unsigned kb = (unsigned)h * 64u;
  if (wid >= 4) {
#pragma unroll
    for (int j = 0; j < 4; ++j)
      gld16(sA4 + (kb + (unsigned)j * (16u * KPB)), lds + sb + (wid - 4) * 4096 + j * 1024);
  } else {
#pragma unroll
    for (int g = 0; g < 6; ++g)
      if (SMASK & (1u << g))
        gld16(sW + ((unsigned)g * GSTR + kb), lds + sb + 16384 + g * 4096 + wid * 1024);
  }
}

template<unsigned CM>
__device__ __forceinline__ void comp(const char* lds, int sb, int aro, int wro,
                                     f32x4 acc[6][4][2]) {
  const char* base = lds + sb;
  bf16x8 a0 = *(const bf16x8*)(base + aro);
  bf16x8 a1 = *(const bf16x8*)(base + aro + 1024);
  bf16x8 a2 = *(const bf16x8*)(base + aro + 2048);
  bf16x8 a3 = *(const bf16x8*)(base + aro + 3072);
  __builtin_amdgcn_s_setprio(1);
#pragma unroll
  for (int g = 0; g < 6; ++g) {
    if (CM & (1u << g)) {
      const char* wb = base + wro + g * 4096;
      bf16x8 b0 = *(const bf16x8*)(wb);
      bf16x8 b1 = *(const bf16x8*)(wb + 1024);
      acc[g][0][0] = __builtin_amdgcn_mfma_f32_16x16x32_bf16(a0, b0, acc[g][0][0], 0, 0, 0);
      acc[g][1][0] = __builtin_amdgcn_mfma_f32_16x16x32_bf16(a1, b0, acc[g][1][0], 0, 0, 0);
      acc[g][2][0] = __builtin_amdgcn_mfma_f32_16x16x32_bf16(a2, b0, acc[g][2][0], 0, 0, 0);
      acc[g][3][0] = __builtin_amdgcn_mfma_f32_16x16x32_bf16(a3, b0, acc[g][3][0], 0, 0, 0);
      acc[g][0][1] = __builtin_amdgcn_mfma_f32_16x16x32_bf16(a0, b1, acc[g][0][1], 0, 0, 0);
      acc[g][1][1] = __builtin_amdgcn_mfma_f32_16x16x32_bf16(a1, b1, acc[g][1][1], 0, 0, 0);
      acc[g][2][1] = __builtin_amdgcn_mfma_f32_16x16x32_bf16(a2, b1, acc[g][2][1], 0, 0, 0);
      acc[g][3][1] = __builtin_amdgcn_mfma_f32_16x16x32_bf16(a3, b1, acc[g][3][1], 0, 0, 0);
    }
  }
  __builtin_amdgcn_s_setprio(0);
}

template<unsigned CM, unsigned SM, bool ST>
__device__ __forceinline__ void phase(char* lds, int h, const char* sA4, const char* sW,
                                      int wid, int aro, int wro, f32x4 acc[6][4][2]) {
  if (ST) stage<SM>(lds, ((h + 1) & 1) * SLOT, h + 1, sA4, sW, wid);
  comp<CM>(lds, (h & 1) * SLOT, aro, wro, acc);
  __syncthreads();   // drains stage(h+1) (overlapped by co-resident wg) + slot handoff
}

// ---------------- main fused kernel ----------------
__global__ __launch_bounds__(512, 4) void lstm_main(
    const unsigned short* __restrict__ Ap, const unsigned short* __restrict__ Wp,
    const float* __restrict__ c_prev,
    const float* __restrict__ b_ix, const float* __restrict__ b_fx,
    const float* __restrict__ b_tx, const float* __restrict__ b_cx,
    const float* __restrict__ b_ox,
    float* __restrict__ out)
{
  __shared__ __align__(16) char lds[2 * SLOT];   // 81920 B -> exactly 2 wgs/CU

  const int tid  = threadIdx.x;
  const int lane = tid & 63;
  const int wid  = tid >> 6;

  // XCD swizzle: XCD k owns col-block k (W slice ~1MB, L2-resident); 512 wgs all resident
  const int bid = blockIdx.x;
  const int cb  = bid & 7;                   // 0..7
  const int rb  = bid >> 3;                  // 0..63
  const unsigned brow = (unsigned)rb * 256u;
  const int bcol = cb * 64;

  const int wr  = (wid >> 1) * 64;           // wave rows [wr, wr+64)
  const int wcg = (wid & 1) * 32;            // wave cols [wcg, wcg+32)
  const int lrow = lane & 15;
  const int kgrp = lane >> 4;

  f32x4 acc[6][4][2];
  {
    f32x4 z = {0.f, 0.f, 0.f, 0.f};
#pragma unroll
    for (int g = 0; g < 6; ++g)
#pragma unroll
      for (int i = 0; i < 4; ++i) { acc[g][i][0] = z; acc[g][i][1] = z; }
  }

  // swizzled read offsets
  const int sread = ((kgrp + (lrow >> 1)) & 3) << 4;
  const int aro = (wr + lrow) * 64 + sread;
  const int wro = 16384 + (wcg + lrow) * 64 + sread;

  // stage source pointers (per-lane pre-permuted granule; r4-verified math)
  const int l4 = lane >> 2;
  const int kslot = (((lane & 3) - ((lane >> 3) & 3)) & 3) << 4;
  const int w4 = (wid >= 4) ? (wid - 4) : 0;
  const char* sA4 = (const char*)Ap + (size_t)(brow + w4 * 64 + l4) * KPB + kslot;
  const char* sW  = (const char*)Wp + (size_t)(bcol + wid * 16 + l4) * KPB + kslot;

  // prologue
  stage<0x1F>(lds, 0, 0, sA4, sW, wid);
  __syncthreads();

#pragma unroll 1
  for (int h = 0; h < 7; ++h)
    phase<0x1F, 0x1F, true>(lds, h, sA4, sW, wid, aro, wro, acc);
  phase<0x1F, 0x1B, true>(lds, 7, sA4, sW, wid, aro, wro, acc);
#pragma unroll 1
  for (int h = 8; h < 23; ++h)
    phase<0x1B, 0x1B, true>(lds, h, sA4, sW, wid, aro, wro, acc);
  phase<0x1B, 0x13, true>(lds, 23, sA4, sW, wid, aro, wro, acc);
#pragma unroll 1
  for (int h = 24; h < 39; ++h)
    phase<0x13, 0x13, true>(lds, h, sA4, sW, wid, aro, wro, acc);
  phase<0x13, 0x30, true>(lds, 39, sA4, sW, wid, aro, wro, acc);
  comp<0x30>(lds, (40 & 1) * SLOT, aro, wro, acc);

  // ---------------- fused epilogue ----------------
  const int n0 = bcol + wcg + lrow;
  const int rbase = kgrp * 4;
#pragma unroll
  for (int cf = 0; cf < 2; ++cf) {
    const int n = n0 + 16 * cf;
    const float bi  = b_ix[n], bff = b_fx[n], bt = b_tx[n], bc = b_cx[n], bo = b_ox[n];
#pragma unroll
    for (int i = 0; i < 4; ++i) {
#pragma unroll
      for (int r = 0; r < 4; ++r) {
        const long m   = (long)brow + wr + 16 * i + rbase + r;
        const long off = m * H_SZ + n;
        const float iv = sigm(acc[0][i][cf][r] + bi);
        const float fv = sigm(acc[1][i][cf][r] + bff);
        const float Tv = sigm(acc[2][i][cf][r] + bt + sigm(acc[5][i][cf][r]));
        const float kv = tanhx(acc[3][i][cf][r] + bc);
        const float ov = sigm(acc[4][i][cf][r] + bo);
        const float cp = c_prev[off];
        const float cn = iv * Tv * kv + fv * cp;
        out[off]          = ov * tanhx(cn);
        out[BH + off]     = cn;
        out[2 * BH + off] = Tv;
      }
    }
  }
}

extern "C" void kernel_launch(void* const* d_in, const int* in_sizes, int n_in,
                              void* d_out, int out_size, void* d_ws, size_t ws_size,
                              hipStream_t stream) {
  const float* x      = (const float*)d_in[0];
  const float* h      = (const float*)d_in[1];
  const float* c_prev = (const float*)d_in[2];
  const float* dl     = (const float*)d_in[3];
  const float* W_ix = (const float*)d_in[4];
  const float* b_ix = (const float*)d_in[5];
  const float* W_ih = (const float*)d_in[6];
  const float* W_ic = (const float*)d_in[7];
  const float* W_fx = (const float*)d_in[8];
  const float* b_fx = (const float*)d_in[9];
  const float* W_fh = (const float*)d_in[10];
  const float* W_fc = (const float*)d_in[11];
  const float* W_tx = (const float*)d_in[12];
  const float* b_tx = (const float*)d_in[13];
  const float* W_tt = (const float*)d_in[14];
  const float* W_cx = (const float*)d_in[15];
  const float* b_cx = (const float*)d_in[16];
  const float* W_ch = (const float*)d_in[17];
  const float* W_ox = (const float*)d_in[18];
  const float* b_ox = (const float*)d_in[19];
  const float* W_oh = (const float*)d_in[20];
  const float* W_oc = (const float*)d_in[21];
  const float* W_ot = (const float*)d_in[22];

  unsigned short* Ap = (unsigned short*)d_ws;                                   // 44.04 MB
  unsigned short* Wp = (unsigned short*)((char*)d_ws + (size_t)B_SZ * KP * 2);  // +8.26 MB

  const long na4 = (long)B_SZ * KP / 4;
  prep_a_kernel<<<(int)((na4 + 255) / 256), 256, 0, stream>>>(x, h, c_prev, dl, Ap);
  const long nw4 = 6L * H_SZ * KP / 4;
  prep_w_kernel<<<(int)((nw4 + 255) / 256), 256, 0, stream>>>(
      W_ix, W_ih, W_ic, W_fx, W_fh, W_fc, W_tx, W_tt, W_cx, W_ch,
      W_ox, W_oh, W_oc, W_ot, Wp);

  lstm_main<<<512, 512, 0, stream>>>(Ap, Wp, c_prev, b_ix, b_fx, b_tx, b_cx, b_ox,
                                     (float*)d_out);
}

// Round 7
// 140.952 us; speedup vs baseline: 3.7745x; 3.7745x over previous
//
#include <hip/hip_runtime.h>
#include <cstdint>

#define B_SZ   16384
#define H_SZ   512
#define DIN    256
#define TEMB   16
#define KP     1344          // packed K: x[0,256) h[256,768) c[768,1280) delt[1280,1296) pad[1296,1344)
#define KPB    2688          // KP*2 bytes per row
#define BH     8388608L      // B_SZ*H_SZ
#define SLOT   49152         // LDS slot: A 8 KB (128 rows x 64 B) + W 5 regions x 8 KB
#define GSTR   1376256       // 512*KPB: gate stride in Wp bytes

typedef __attribute__((ext_vector_type(4))) float f32x4;
typedef __bf16 bf16x8 __attribute__((ext_vector_type(8)));

typedef const __attribute__((address_space(1))) unsigned int gu32_t;
typedef __attribute__((address_space(3)))       unsigned int lu32_t;

// gate -> W region (t and tt share region 4: never co-active)
__device__ constexpr int RG[6] = {0, 1, 4, 3, 2, 4};

__device__ __forceinline__ void gld16(const void* g, void* l) {
  __builtin_amdgcn_global_load_lds((gu32_t*)(uintptr_t)g,
                                   (lu32_t*)(unsigned int)(uintptr_t)l, 16, 0, 0);
}

__device__ __forceinline__ unsigned short f2bf(float f) {
  unsigned int u = __float_as_uint(f);
  u += 0x7FFFu + ((u >> 16) & 1u);   // RNE; inputs finite
  return (unsigned short)(u >> 16);
}

__device__ __forceinline__ float sigm(float v)  { return 1.0f / (1.0f + __expf(-v)); }
__device__ __forceinline__ float tanhx(float v) { return 2.0f / (1.0f + __expf(-2.0f * v)) - 1.0f; }

// ---------------- prep: pack A = [x|h|c|delt|0] as bf16 [B][KP] ----------------
__global__ void prep_a_kernel(const float* __restrict__ x, const float* __restrict__ h,
                              const float* __restrict__ c, const float* __restrict__ dl,
                              unsigned short* __restrict__ Ap) {
  long idx = (long)blockIdx.x * 256 + threadIdx.x;
  const long n4 = (long)B_SZ * KP / 4;
  if (idx >= n4) return;
  int row = (int)(idx / (KP / 4));
  int k4  = (int)(idx % (KP / 4)) * 4;
  float4 v = make_float4(0.f, 0.f, 0.f, 0.f);
  if (k4 < 256)       v = *(const float4*)(x  + (long)row * DIN  + k4);
  else if (k4 < 768)  v = *(const float4*)(h  + (long)row * H_SZ + (k4 - 256));
  else if (k4 < 1280) v = *(const float4*)(c  + (long)row * H_SZ + (k4 - 768));
  else if (k4 < 1296) v = *(const float4*)(dl + (long)row * TEMB + (k4 - 1280));
  ushort4 o;
  o.x = f2bf(v.x); o.y = f2bf(v.y); o.z = f2bf(v.z); o.w = f2bf(v.w);
  *(ushort4*)(Ap + idx * 4) = o;
}

// ---------------- prep: pack Wp[6][512][KP] bf16 ----------------
__global__ void prep_w_kernel(const float* __restrict__ Wix, const float* __restrict__ Wih, const float* __restrict__ Wic,
                              const float* __restrict__ Wfx, const float* __restrict__ Wfh, const float* __restrict__ Wfc,
                              const float* __restrict__ Wtx, const float* __restrict__ Wtt,
                              const float* __restrict__ Wcx, const float* __restrict__ Wch,
                              const float* __restrict__ Wox, const float* __restrict__ Woh,
                              const float* __restrict__ Woc, const float* __restrict__ Wot,
                              unsigned short* __restrict__ Wp) {
  long idx = (long)blockIdx.x * 256 + threadIdx.x;
  const long n4 = 6L * H_SZ * KP / 4;
  if (idx >= n4) return;
  int k4   = (int)(idx % (KP / 4)) * 4;
  int rest = (int)(idx / (KP / 4));
  int n = rest & 511;
  int g = rest >> 9;
  const float* src = nullptr; long o = 0;
  if (g == 0) {
    if (k4 < 256)       { src = Wix; o = (long)n * 256 + k4; }
    else if (k4 < 768)  { src = Wih; o = (long)n * 512 + (k4 - 256); }
    else if (k4 < 1280) { src = Wic; o = (long)n * 512 + (k4 - 768); }
  } else if (g == 1) {
    if (k4 < 256)       { src = Wfx; o = (long)n * 256 + k4; }
    else if (k4 < 768)  { src = Wfh; o = (long)n * 512 + (k4 - 256); }
    else if (k4 < 1280) { src = Wfc; o = (long)n * 512 + (k4 - 768); }
  } else if (g == 2) {
    if (k4 < 256)       { src = Wtx; o = (long)n * 256 + k4; }
  } else if (g == 3) {
    if (k4 < 256)       { src = Wcx; o = (long)n * 256 + k4; }
    else if (k4 < 768)  { src = Wch; o = (long)n * 512 + (k4 - 256); }
  } else if (g == 4) {
    if (k4 < 256)       { src = Wox; o = (long)n * 256 + k4; }
    else if (k4 < 768)  { src = Woh; o = (long)n * 512 + (k4 - 256); }
    else if (k4 < 1280) { src = Woc; o = (long)n * 512 + (k4 - 768); }
    else if (k4 < 1296) { src = Wot; o = (long)n * 16 + (k4 - 1280); }
  } else {
    if (k4 >= 1280 && k4 < 1296) { src = Wtt; o = (long)n * 16 + (k4 - 1280); }
  }
  float4 v = make_float4(0.f, 0.f, 0.f, 0.f);
  if (src) v = *(const float4*)(src + o);
  ushort4 u;
  u.x = f2bf(v.x); u.y = f2bf(v.y); u.z = f2bf(v.z); u.w = f2bf(v.w);
  *(ushort4*)(Wp + idx * 4) = u;
}

// LDS layout per slot (K-phase = 32 elems = 64 B per row):
//   A: byte = row*64 + ((kgrp + (row>>1))&3)*16,  row in [0,128)
//   W: byte = 8192 + RG[g]*8192 + col*64 + ((kgrp+(col>>1))&3)*16
// gld16 writes 1KB chunks (16 rows) linearly; per-lane source granule is
// pre-permuted (kslot) so the stored layout matches (linear-dest rule, r4-verified).

// stage half-tile ht into slot at byte base sb; 1+popcount(SMASK) loads per wave
template<unsigned SMASK>
__device__ __forceinline__ void stage(char* lds, int sb, int ht,
                                      const char* sA, const char* sW, int wid) {
  const unsigned kb = (unsigned)ht * 64u;
  gld16(sA + kb, lds + sb + wid * 1024);
#pragma unroll
  for (int g = 0; g < 6; ++g)
    if (SMASK & (1u << g))
      gld16(sW + (unsigned)g * GSTR + kb, lds + sb + 8192 + RG[g] * 8192 + wid * 1024);
}

template<unsigned CM>
__device__ __forceinline__ void comp(const char* lds, int rs, int aro, int wro,
                                     f32x4 acc[6][4][2]) {
  const char* base = lds + rs;
  bf16x8 a0 = *(const bf16x8*)(base + aro);
  bf16x8 a1 = *(const bf16x8*)(base + aro + 1024);
  bf16x8 a2 = *(const bf16x8*)(base + aro + 2048);
  bf16x8 a3 = *(const bf16x8*)(base + aro + 3072);
  __builtin_amdgcn_s_setprio(1);
#pragma unroll
  for (int g = 0; g < 6; ++g) {
    if (CM & (1u << g)) {
      const char* wb = base + 8192 + RG[g] * 8192 + wro;
      bf16x8 b0 = *(const bf16x8*)(wb);
      bf16x8 b1 = *(const bf16x8*)(wb + 1024);
      acc[g][0][0] = __builtin_amdgcn_mfma_f32_16x16x32_bf16(a0, b0, acc[g][0][0], 0, 0, 0);
      acc[g][1][0] = __builtin_amdgcn_mfma_f32_16x16x32_bf16(a1, b0, acc[g][1][0], 0, 0, 0);
      acc[g][2][0] = __builtin_amdgcn_mfma_f32_16x16x32_bf16(a2, b0, acc[g][2][0], 0, 0, 0);
      acc[g][3][0] = __builtin_amdgcn_mfma_f32_16x16x32_bf16(a3, b0, acc[g][3][0], 0, 0, 0);
      acc[g][0][1] = __builtin_amdgcn_mfma_f32_16x16x32_bf16(a0, b1, acc[g][0][1], 0, 0, 0);
      acc[g][1][1] = __builtin_amdgcn_mfma_f32_16x16x32_bf16(a1, b1, acc[g][1][1], 0, 0, 0);
      acc[g][2][1] = __builtin_amdgcn_mfma_f32_16x16x32_bf16(a2, b1, acc[g][2][1], 0, 0, 0);
      acc[g][3][1] = __builtin_amdgcn_mfma_f32_16x16x32_bf16(a3, b1, acc[g][3][1], 0, 0, 0);
    }
  }
  __builtin_amdgcn_s_setprio(0);
}

// single-barrier phase: vmcnt(N) -> barrier -> stage(h+2) -> compute(h)
// ring-3 makes the end barrier unnecessary: stage(h+2) writes the slot last
// read in phase h-1, and every wave passed this barrier only after finishing
// phase h-1's reads.
template<unsigned CM, unsigned SM, int NW, bool ST>
__device__ __forceinline__ void phase(char* lds, int rs, int ws, int ht,
    const char* sA, const char* sW, int wid, int aro, int wro, f32x4 acc[6][4][2]) {
  asm volatile("s_waitcnt vmcnt(%0)" :: "i"(NW) : "memory");
  __builtin_amdgcn_s_barrier();
  __builtin_amdgcn_sched_barrier(0);     // nothing moves above the barrier
  if (ST) stage<SM>(lds, ws, ht, sA, sW, wid);
  comp<CM>(lds, rs, aro, wro, acc);
}

// ---------------- main fused kernel ----------------
__global__ __launch_bounds__(512, 2) void lstm_main(
    const unsigned short* __restrict__ Ap, const unsigned short* __restrict__ Wp,
    const float* __restrict__ c_prev,
    const float* __restrict__ b_ix, const float* __restrict__ b_fx,
    const float* __restrict__ b_tx, const float* __restrict__ b_cx,
    const float* __restrict__ b_ox,
    float* __restrict__ out)
{
  __shared__ __align__(16) char lds[3 * SLOT];   // 147456 B, 1 wg/CU

  const int tid  = threadIdx.x;
  const int lane = tid & 63;
  const int wid  = tid >> 6;

  // XCD swizzle: XCD pair {2c,2c+1} owns col-block c (W slice ~2MB, L2-resident)
  const int bid = blockIdx.x;
  const int xcd = bid & 7;
  const int idx = bid >> 3;                  // 0..63
  const int cb  = xcd >> 1;                  // 0..3
  const int rb  = (idx << 1) | (xcd & 1);    // 0..127
  const unsigned brow = (unsigned)rb * 128u;
  const int bcol = cb * 128;

  const int wr  = (wid >> 2) * 64;           // wave rows [wr, wr+64)
  const int wcg = (wid & 3) * 32;            // wave cols [wcg, wcg+32)
  const int lrow = lane & 15;
  const int kgrp = lane >> 4;

  f32x4 acc[6][4][2];
  {
    f32x4 z = {0.f, 0.f, 0.f, 0.f};
#pragma unroll
    for (int g = 0; g < 6; ++g)
#pragma unroll
      for (int i = 0; i < 4; ++i) { acc[g][i][0] = z; acc[g][i][1] = z; }
  }

  // swizzled read offsets
  const int sread = ((kgrp + (lrow >> 1)) & 3) << 4;
  const int aro = (wr + lrow) * 64 + sread;
  const int wro = (wcg + lrow) * 64 + sread;   // region-relative

  // stage source pointers (per-lane pre-permuted granule; r4-verified math)
  const int l4 = lane >> 2;
  const int kslot = (((lane & 3) - ((lane >> 3) & 3)) & 3) << 4;
  const char* sA = (const char*)Ap + (size_t)(brow + wid * 16 + l4) * KPB + kslot;
  const char* sW = (const char*)Wp + (size_t)(bcol + wid * 16 + l4) * KPB + kslot;

  // prologue: half-tiles 0,1 in flight
  stage<0x1F>(lds, 0,    0, sA, sW, wid);
  stage<0x1F>(lds, SLOT, 1, sA, sW, wid);

  int rs = 0;
#define PH(CMv, SMv, NWv, STv, HT) do {                                        \
    int ws = (rs >= SLOT) ? rs - SLOT : rs + 2 * SLOT;                         \
    phase<CMv, SMv, NWv, STv>(lds, rs, ws, HT, sA, sW, wid, aro, wro, acc);    \
    rs = (rs == 2 * SLOT) ? 0 : rs + SLOT;                                     \
  } while (0)

#pragma unroll 1
  for (int h = 0; h < 6; ++h) PH(0x1F, 0x1F, 6, true, h + 2);
  PH(0x1F, 0x1B, 6, true, 8);
  PH(0x1F, 0x1B, 5, true, 9);
#pragma unroll 1
  for (int h = 8; h < 22; ++h) PH(0x1B, 0x1B, 5, true, h + 2);
  PH(0x1B, 0x13, 5, true, 24);
  PH(0x1B, 0x13, 4, true, 25);
#pragma unroll 1
  for (int h = 24; h < 38; ++h) PH(0x13, 0x13, 4, true, h + 2);
  PH(0x13, 0x30, 4, true, 40);
  PH(0x13, 0x00, 3, false, 0);
  PH(0x30, 0x00, 0, false, 0);
#undef PH

  // ---------------- fused epilogue ----------------
  const int n0 = bcol + wcg + lrow;
  const int rbase = kgrp * 4;
#pragma unroll
  for (int cf = 0; cf < 2; ++cf) {
    const int n = n0 + 16 * cf;
    const float bi  = b_ix[n], bff = b_fx[n], bt = b_tx[n], bc = b_cx[n], bo = b_ox[n];
#pragma unroll
    for (int i = 0; i < 4; ++i) {
#pragma unroll
      for (int r = 0; r < 4; ++r) {
        const long m   = (long)brow + wr + 16 * i + rbase + r;
        const long off = m * H_SZ + n;
        const float iv = sigm(acc[0][i][cf][r] + bi);
        const float fv = sigm(acc[1][i][cf][r] + bff);
        const float Tv = sigm(acc[2][i][cf][r] + bt + sigm(acc[5][i][cf][r]));
        const float kv = tanhx(acc[3][i][cf][r] + bc);
        const float ov = sigm(acc[4][i][cf][r] + bo);
        const float cp = c_prev[off];
        const float cn = iv * Tv * kv + fv * cp;
        out[off]          = ov * tanhx(cn);
        out[BH + off]     = cn;
        out[2 * BH + off] = Tv;
      }
    }
  }
}

extern "C" void kernel_launch(void* const* d_in, const int* in_sizes, int n_in,
                              void* d_out, int out_size, void* d_ws, size_t ws_size,
                              hipStream_t stream) {
  const float* x      = (const float*)d_in[0];
  const float* h      = (const float*)d_in[1];
  const float* c_prev = (const float*)d_in[2];
  const float* dl     = (const float*)d_in[3];
  const float* W_ix = (const float*)d_in[4];
  const float* b_ix = (const float*)d_in[5];
  const float* W_ih = (const float*)d_in[6];
  const float* W_ic = (const float*)d_in[7];
  const float* W_fx = (const float*)d_in[8];
  const float* b_fx = (const float*)d_in[9];
  const float* W_fh = (const float*)d_in[10];
  const float* W_fc = (const float*)d_in[11];
  const float* W_tx = (const float*)d_in[12];
  const float* b_tx = (const float*)d_in[13];
  const float* W_tt = (const float*)d_in[14];
  const float* W_cx = (const float*)d_in[15];
  const float* b_cx = (const float*)d_in[16];
  const float* W_ch = (const float*)d_in[17];
  const float* W_ox = (const float*)d_in[18];
  const float* b_ox = (const float*)d_in[19];
  const float* W_oh = (const float*)d_in[20];
  const float* W_oc = (const float*)d_in[21];
  const float* W_ot = (const float*)d_in[22];

  unsigned short* Ap = (unsigned short*)d_ws;                                   // 44.04 MB
  unsigned short* Wp = (unsigned short*)((char*)d_ws + (size_t)B_SZ * KP * 2);  // +8.26 MB

  const long na4 = (long)B_SZ * KP / 4;
  prep_a_kernel<<<(int)((na4 + 255) / 256), 256, 0, stream>>>(x, h, c_prev, dl, Ap);
  const long nw4 = 6L * H_SZ * KP / 4;
  prep_w_kernel<<<(int)((nw4 + 255) / 256), 256, 0, stream>>>(
      W_ix, W_ih, W_ic, W_fx, W_fh, W_fc, W_tx, W_tt, W_cx, W_ch,
      W_ox, W_oh, W_oc, W_ot, Wp);

  lstm_main<<<512, 512, 0, stream>>>(Ap, Wp, c_prev, b_ix, b_fx, b_tx, b_cx, b_ox,
                                     (float*)d_out);
}

// Round 8
// 138.640 us; speedup vs baseline: 3.8374x; 1.0167x over previous
//
#include <hip/hip_runtime.h>
#include <cstdint>

#define B_SZ   16384
#define H_SZ   512
#define DIN    256
#define TEMB   16
#define KP     1344          // packed K: x[0,256) h[256,768) c[768,1280) delt[1280,1296) pad[1296,1344)
#define KPB    2688          // KP*2 bytes per row
#define BH     8388608L      // B_SZ*H_SZ
#define SLOT   49152         // LDS slot: A 8 KB (128 rows x 64 B) + W 5 regions x 8 KB
#define GSTR   1376256       // 512*KPB: gate stride in Wp bytes

typedef __attribute__((ext_vector_type(4))) float f32x4;
typedef __bf16 bf16x8 __attribute__((ext_vector_type(8)));

typedef const __attribute__((address_space(1))) unsigned int gu32_t;
typedef __attribute__((address_space(3)))       unsigned int lu32_t;

// gate -> W region (t and tt share region 4: never co-active)
__device__ constexpr int RG[6] = {0, 1, 4, 3, 2, 4};

__device__ __forceinline__ void gld16(const void* g, void* l) {
  __builtin_amdgcn_global_load_lds((gu32_t*)(uintptr_t)g,
                                   (lu32_t*)(unsigned int)(uintptr_t)l, 16, 0, 0);
}

__device__ __forceinline__ unsigned short f2bf(float f) {
  unsigned int u = __float_as_uint(f);
  u += 0x7FFFu + ((u >> 16) & 1u);   // RNE; inputs finite
  return (unsigned short)(u >> 16);
}

__device__ __forceinline__ float sigm(float v)  { return 1.0f / (1.0f + __expf(-v)); }
__device__ __forceinline__ float tanhx(float v) { return 2.0f / (1.0f + __expf(-2.0f * v)) - 1.0f; }

// ---------------- prep: pack A = [x|h|c|delt|0] as bf16 [B][KP] ----------------
__global__ void prep_a_kernel(const float* __restrict__ x, const float* __restrict__ h,
                              const float* __restrict__ c, const float* __restrict__ dl,
                              unsigned short* __restrict__ Ap) {
  long idx = (long)blockIdx.x * 256 + threadIdx.x;
  const long n4 = (long)B_SZ * KP / 4;
  if (idx >= n4) return;
  int row = (int)(idx / (KP / 4));
  int k4  = (int)(idx % (KP / 4)) * 4;
  float4 v = make_float4(0.f, 0.f, 0.f, 0.f);
  if (k4 < 256)       v = *(const float4*)(x  + (long)row * DIN  + k4);
  else if (k4 < 768)  v = *(const float4*)(h  + (long)row * H_SZ + (k4 - 256));
  else if (k4 < 1280) v = *(const float4*)(c  + (long)row * H_SZ + (k4 - 768));
  else if (k4 < 1296) v = *(const float4*)(dl + (long)row * TEMB + (k4 - 1280));
  ushort4 o;
  o.x = f2bf(v.x); o.y = f2bf(v.y); o.z = f2bf(v.z); o.w = f2bf(v.w);
  *(ushort4*)(Ap + idx * 4) = o;
}

// ---------------- prep: pack Wp[6][512][KP] bf16 ----------------
__global__ void prep_w_kernel(const float* __restrict__ Wix, const float* __restrict__ Wih, const float* __restrict__ Wic,
                              const float* __restrict__ Wfx, const float* __restrict__ Wfh, const float* __restrict__ Wfc,
                              const float* __restrict__ Wtx, const float* __restrict__ Wtt,
                              const float* __restrict__ Wcx, const float* __restrict__ Wch,
                              const float* __restrict__ Wox, const float* __restrict__ Woh,
                              const float* __restrict__ Woc, const float* __restrict__ Wot,
                              unsigned short* __restrict__ Wp) {
  long idx = (long)blockIdx.x * 256 + threadIdx.x;
  const long n4 = 6L * H_SZ * KP / 4;
  if (idx >= n4) return;
  int k4   = (int)(idx % (KP / 4)) * 4;
  int rest = (int)(idx / (KP / 4));
  int n = rest & 511;
  int g = rest >> 9;
  const float* src = nullptr; long o = 0;
  if (g == 0) {
    if (k4 < 256)       { src = Wix; o = (long)n * 256 + k4; }
    else if (k4 < 768)  { src = Wih; o = (long)n * 512 + (k4 - 256); }
    else if (k4 < 1280) { src = Wic; o = (long)n * 512 + (k4 - 768); }
  } else if (g == 1) {
    if (k4 < 256)       { src = Wfx; o = (long)n * 256 + k4; }
    else if (k4 < 768)  { src = Wfh; o = (long)n * 512 + (k4 - 256); }
    else if (k4 < 1280) { src = Wfc; o = (long)n * 512 + (k4 - 768); }
  } else if (g == 2) {
    if (k4 < 256)       { src = Wtx; o = (long)n * 256 + k4; }
  } else if (g == 3) {
    if (k4 < 256)       { src = Wcx; o = (long)n * 256 + k4; }
    else if (k4 < 768)  { src = Wch; o = (long)n * 512 + (k4 - 256); }
  } else if (g == 4) {
    if (k4 < 256)       { src = Wox; o = (long)n * 256 + k4; }
    else if (k4 < 768)  { src = Woh; o = (long)n * 512 + (k4 - 256); }
    else if (k4 < 1280) { src = Woc; o = (long)n * 512 + (k4 - 768); }
    else if (k4 < 1296) { src = Wot; o = (long)n * 16 + (k4 - 1280); }
  } else {
    if (k4 >= 1280 && k4 < 1296) { src = Wtt; o = (long)n * 16 + (k4 - 1280); }
  }
  float4 v = make_float4(0.f, 0.f, 0.f, 0.f);
  if (src) v = *(const float4*)(src + o);
  ushort4 u;
  u.x = f2bf(v.x); u.y = f2bf(v.y); u.z = f2bf(v.z); u.w = f2bf(v.w);
  *(ushort4*)(Wp + idx * 4) = u;
}

// LDS layout per slot (K-phase = 32 elems = 64 B per row):
//   A: byte = row*64 + ((kgrp + (row>>1))&3)*16,  row in [0,128)
//   W: byte = 8192 + RG[g]*8192 + col*64 + ((kgrp+(col>>1))&3)*16
// gld16 writes 1KB chunks (16 rows) linearly; per-lane source granule is
// pre-permuted (kslot) so the stored layout matches (linear-dest rule, r4-verified).

// stage half-tile ht into slot at byte base sb; 1+popcount(SMASK) loads per wave
template<unsigned SMASK>
__device__ __forceinline__ void stage(char* lds, int sb, int ht,
                                      const char* sA, const char* sW, int wid) {
  const unsigned kb = (unsigned)ht * 64u;
  gld16(sA + kb, lds + sb + wid * 1024);
#pragma unroll
  for (int g = 0; g < 6; ++g)
    if (SMASK & (1u << g))
      gld16(sW + (unsigned)g * GSTR + kb, lds + sb + 8192 + RG[g] * 8192 + wid * 1024);
}

// sub-phase-split phase (T3): SP1 = {A+b0 reads, stage issue, lgkm(0), pure MFMA cf=0};
// SP2 = {b1 reads (float into SP1's MFMA shadow), lgkm(0), pure MFMA cf=1}.
// ONE s_barrier per phase; SP2's lgkmcnt(0) drains all slot-h reads before the
// next phase's barrier, so stage(h+3)'s overwrite of slot h cannot race them.
template<unsigned CM, unsigned SM, int NW, bool ST>
__device__ __forceinline__ void phase(char* lds, int rs, int ws, int ht,
    const char* sA, const char* sW, int wid, int aro, int wro, f32x4 acc[6][4][2]) {
  asm volatile("s_waitcnt vmcnt(%0)" :: "i"(NW) : "memory");   // slot h landed (this wave's view)
  __builtin_amdgcn_s_barrier();                                 // all waves' loads landed
  __builtin_amdgcn_sched_barrier(0);
  const char* base = lds + rs;
  // ---- SP1 reads ----
  bf16x8 a0 = *(const bf16x8*)(base + aro);
  bf16x8 a1 = *(const bf16x8*)(base + aro + 1024);
  bf16x8 a2 = *(const bf16x8*)(base + aro + 2048);
  bf16x8 a3 = *(const bf16x8*)(base + aro + 3072);
  bf16x8 b0[6];
#pragma unroll
  for (int g = 0; g < 6; ++g)
    if (CM & (1u << g))
      b0[g] = *(const bf16x8*)(base + 8192 + RG[g] * 8192 + wro);
  if (ST) stage<SM>(lds, ws, ht, sA, sW, wid);   // issue-only; rides vmcnt
  asm volatile("s_waitcnt lgkmcnt(0)" ::: "memory");
  __builtin_amdgcn_sched_barrier(0);             // rule #18: MFMA must not hoist above
  __builtin_amdgcn_s_setprio(1);
#pragma unroll
  for (int g = 0; g < 6; ++g) {
    if (CM & (1u << g)) {
      acc[g][0][0] = __builtin_amdgcn_mfma_f32_16x16x32_bf16(a0, b0[g], acc[g][0][0], 0, 0, 0);
      acc[g][1][0] = __builtin_amdgcn_mfma_f32_16x16x32_bf16(a1, b0[g], acc[g][1][0], 0, 0, 0);
      acc[g][2][0] = __builtin_amdgcn_mfma_f32_16x16x32_bf16(a2, b0[g], acc[g][2][0], 0, 0, 0);
      acc[g][3][0] = __builtin_amdgcn_mfma_f32_16x16x32_bf16(a3, b0[g], acc[g][3][0], 0, 0, 0);
    }
  }
  __builtin_amdgcn_s_setprio(0);
  // ---- SP2 ----
  bf16x8 b1[6];
#pragma unroll
  for (int g = 0; g < 6; ++g)
    if (CM & (1u << g))
      b1[g] = *(const bf16x8*)(base + 8192 + RG[g] * 8192 + wro + 1024);
  asm volatile("s_waitcnt lgkmcnt(0)" ::: "memory");
  __builtin_amdgcn_sched_barrier(0);
  __builtin_amdgcn_s_setprio(1);
#pragma unroll
  for (int g = 0; g < 6; ++g) {
    if (CM & (1u << g)) {
      acc[g][0][1] = __builtin_amdgcn_mfma_f32_16x16x32_bf16(a0, b1[g], acc[g][0][1], 0, 0, 0);
      acc[g][1][1] = __builtin_amdgcn_mfma_f32_16x16x32_bf16(a1, b1[g], acc[g][1][1], 0, 0, 0);
      acc[g][2][1] = __builtin_amdgcn_mfma_f32_16x16x32_bf16(a2, b1[g], acc[g][2][1], 0, 0, 0);
      acc[g][3][1] = __builtin_amdgcn_mfma_f32_16x16x32_bf16(a3, b1[g], acc[g][3][1], 0, 0, 0);
    }
  }
  __builtin_amdgcn_s_setprio(0);
}

// ---------------- main fused kernel ----------------
__global__ __launch_bounds__(512, 2) void lstm_main(
    const unsigned short* __restrict__ Ap, const unsigned short* __restrict__ Wp,
    const float* __restrict__ c_prev,
    const float* __restrict__ b_ix, const float* __restrict__ b_fx,
    const float* __restrict__ b_tx, const float* __restrict__ b_cx,
    const float* __restrict__ b_ox,
    float* __restrict__ out)
{
  __shared__ __align__(16) char lds[3 * SLOT];   // 147456 B, 1 wg/CU

  const int tid  = threadIdx.x;
  const int lane = tid & 63;
  const int wid  = tid >> 6;

  // XCD swizzle: XCD pair {2c,2c+1} owns col-block c (W slice ~2MB, L2-resident)
  const int bid = blockIdx.x;
  const int xcd = bid & 7;
  const int idx = bid >> 3;                  // 0..63
  const int cb  = xcd >> 1;                  // 0..3
  const int rb  = (idx << 1) | (xcd & 1);    // 0..127
  const unsigned brow = (unsigned)rb * 128u;
  const int bcol = cb * 128;

  const int wr  = (wid >> 2) * 64;           // wave rows [wr, wr+64)
  const int wcg = (wid & 3) * 32;            // wave cols [wcg, wcg+32)
  const int lrow = lane & 15;
  const int kgrp = lane >> 4;

  f32x4 acc[6][4][2];
  {
    f32x4 z = {0.f, 0.f, 0.f, 0.f};
#pragma unroll
    for (int g = 0; g < 6; ++g)
#pragma unroll
      for (int i = 0; i < 4; ++i) { acc[g][i][0] = z; acc[g][i][1] = z; }
  }

  // swizzled read offsets
  const int sread = ((kgrp + (lrow >> 1)) & 3) << 4;
  const int aro = (wr + lrow) * 64 + sread;
  const int wro = (wcg + lrow) * 64 + sread;   // region-relative

  // stage source pointers (per-lane pre-permuted granule; r4-verified math)
  const int l4 = lane >> 2;
  const int kslot = (((lane & 3) - ((lane >> 3) & 3)) & 3) << 4;
  const char* sA = (const char*)Ap + (size_t)(brow + wid * 16 + l4) * KPB + kslot;
  const char* sW = (const char*)Wp + (size_t)(bcol + wid * 16 + l4) * KPB + kslot;

  // prologue: half-tiles 0,1 in flight
  stage<0x1F>(lds, 0,    0, sA, sW, wid);
  stage<0x1F>(lds, SLOT, 1, sA, sW, wid);

  int rs = 0;
#define PH(CMv, SMv, NWv, STv, HT) do {                                        \
    int ws = (rs >= SLOT) ? rs - SLOT : rs + 2 * SLOT;                         \
    phase<CMv, SMv, NWv, STv>(lds, rs, ws, HT, sA, sW, wid, aro, wro, acc);    \
    rs = (rs == 2 * SLOT) ? 0 : rs + SLOT;                                     \
  } while (0)

#pragma unroll 1
  for (int h = 0; h < 6; ++h) PH(0x1F, 0x1F, 6, true, h + 2);
  PH(0x1F, 0x1B, 6, true, 8);
  PH(0x1F, 0x1B, 5, true, 9);
#pragma unroll 1
  for (int h = 8; h < 22; ++h) PH(0x1B, 0x1B, 5, true, h + 2);
  PH(0x1B, 0x13, 5, true, 24);
  PH(0x1B, 0x13, 4, true, 25);
#pragma unroll 1
  for (int h = 24; h < 38; ++h) PH(0x13, 0x13, 4, true, h + 2);
  PH(0x13, 0x30, 4, true, 40);
  PH(0x13, 0x00, 3, false, 0);
  PH(0x30, 0x00, 0, false, 0);
#undef PH

  // ---------------- fused epilogue ----------------
  const int n0 = bcol + wcg + lrow;
  const int rbase = kgrp * 4;
#pragma unroll
  for (int cf = 0; cf < 2; ++cf) {
    const int n = n0 + 16 * cf;
    const float bi  = b_ix[n], bff = b_fx[n], bt = b_tx[n], bc = b_cx[n], bo = b_ox[n];
#pragma unroll
    for (int i = 0; i < 4; ++i) {
#pragma unroll
      for (int r = 0; r < 4; ++r) {
        const long m   = (long)brow + wr + 16 * i + rbase + r;
        const long off = m * H_SZ + n;
        const float iv = sigm(acc[0][i][cf][r] + bi);
        const float fv = sigm(acc[1][i][cf][r] + bff);
        const float Tv = sigm(acc[2][i][cf][r] + bt + sigm(acc[5][i][cf][r]));
        const float kv = tanhx(acc[3][i][cf][r] + bc);
        const float ov = sigm(acc[4][i][cf][r] + bo);
        const float cp = c_prev[off];
        const float cn = iv * Tv * kv + fv * cp;
        out[off]          = ov * tanhx(cn);
        out[BH + off]     = cn;
        out[2 * BH + off] = Tv;
      }
    }
  }
}

extern "C" void kernel_launch(void* const* d_in, const int* in_sizes, int n_in,
                              void* d_out, int out_size, void* d_ws, size_t ws_size,
                              hipStream_t stream) {
  const float* x      = (const float*)d_in[0];
  const float* h      = (const float*)d_in[1];
  const float* c_prev = (const float*)d_in[2];
  const float* dl     = (const float*)d_in[3];
  const float* W_ix = (const float*)d_in[4];
  const float* b_ix = (const float*)d_in[5];
  const float* W_ih = (const float*)d_in[6];
  const float* W_ic = (const float*)d_in[7];
  const float* W_fx = (const float*)d_in[8];
  const float* b_fx = (const float*)d_in[9];
  const float* W_fh = (const float*)d_in[10];
  const float* W_fc = (const float*)d_in[11];
  const float* W_tx = (const float*)d_in[12];
  const float* b_tx = (const float*)d_in[13];
  const float* W_tt = (const float*)d_in[14];
  const float* W_cx = (const float*)d_in[15];
  const float* b_cx = (const float*)d_in[16];
  const float* W_ch = (const float*)d_in[17];
  const float* W_ox = (const float*)d_in[18];
  const float* b_ox = (const float*)d_in[19];
  const float* W_oh = (const float*)d_in[20];
  const float* W_oc = (const float*)d_in[21];
  const float* W_ot = (const float*)d_in[22];

  unsigned short* Ap = (unsigned short*)d_ws;                                   // 44.04 MB
  unsigned short* Wp = (unsigned short*)((char*)d_ws + (size_t)B_SZ * KP * 2);  // +8.26 MB

  const long na4 = (long)B_SZ * KP / 4;
  prep_a_kernel<<<(int)((na4 + 255) / 256), 256, 0, stream>>>(x, h, c_prev, dl, Ap);
  const long nw4 = 6L * H_SZ * KP / 4;
  prep_w_kernel<<<(int)((nw4 + 255) / 256), 256, 0, stream>>>(
      W_ix, W_ih, W_ic, W_fx, W_fh, W_fc, W_tx, W_tt, W_cx, W_ch,
      W_ox, W_oh, W_oc, W_ot, Wp);

  lstm_main<<<512, 512, 0, stream>>>(Ap, Wp, c_prev, b_ix, b_fx, b_tx, b_cx, b_ox,
                                     (float*)d_out);
}